// Round 1
// baseline (389.153 us; speedup 1.0000x reference)
//
#include <hip/hip_runtime.h>
#include <math.h>

// Problem constants (from reference):
//   input (32,1024) f32; enc_h (2,2048,32,512) f32; Wq (1024,1024); bq (1024)
//   out = [attn_values (32,1024) | attn_scores (32,2048,1)] f32, 98304 floats
namespace {
constexpr int Bb = 32;
constexpr int Tt = 2048;
constexpr int Cc = 1024;
constexpr int Hh = 512;
constexpr int DH = 1024;          // D*HIDDEN
constexpr int NC = 32;            // t-chunks per batch row
constexpr int TC = Tt / NC;       // 64 timesteps per block
constexpr float SCALE = 0.04419417382415922f;  // 1/sqrt(512)
}

__device__ __forceinline__ float dot4(const float4& x, const float4& y) {
    return x.x * y.x + x.y * y.y + x.z * y.z + x.w * y.w;
}
__device__ __forceinline__ void fma4(float4& a, float p, const float4& k) {
    a.x += p * k.x; a.y += p * k.y; a.z += p * k.z; a.w += p * k.w;
}

// K1: query = input @ Wq.T + bq   (also zeroes acc/lsum scratch for K2)
// grid 512 = 32 b * 16 j-chunks, 256 threads
__global__ __launch_bounds__(256) void qproj_kernel(
    const float* __restrict__ input, const float* __restrict__ Wq,
    const float* __restrict__ bq, float* __restrict__ query,
    float* __restrict__ zero_region)
{
    const int gid = blockIdx.x * 256 + threadIdx.x;
    if (gid < Bb * DH + Bb) zero_region[gid] = 0.0f;   // acc + lsum := 0

    __shared__ float s_in[Cc];
    const int b   = blockIdx.x >> 4;
    const int jc  = blockIdx.x & 15;
    const int tid = threadIdx.x;
    ((float4*)s_in)[tid] = ((const float4*)(input + b * Cc))[tid];
    __syncthreads();

    const int wave = tid >> 6, lane = tid & 63;
    const float4* xin = (const float4*)s_in;
    for (int jj = 0; jj < 16; ++jj) {
        const int j = jc * 64 + wave * 16 + jj;
        const float4* wrow = (const float4*)(Wq + j * Cc);
        float partial = 0.f;
        #pragma unroll
        for (int i = 0; i < 4; ++i) {
            float4 w4 = wrow[lane + 64 * i];
            float4 x4 = xin[lane + 64 * i];
            partial += dot4(w4, x4);
        }
        #pragma unroll
        for (int off = 32; off; off >>= 1) partial += __shfl_xor(partial, off, 64);
        if (lane == 0) query[b * DH + j] = partial + bq[j];
    }
}

// K2: fused scores + exp + value accumulation (single pass over enc_h).
// Softmax shift-invariance + tiny |s| (<~0.8) => no max subtraction needed.
// grid 1024 = 32 b * 32 chunks, 256 threads (4 waves, 16 t each, 2-t unroll)
__global__ __launch_bounds__(256) void attn_kernel(
    const float* __restrict__ enc_h, const float* __restrict__ query,
    float* __restrict__ acc, float* __restrict__ lsum,
    float* __restrict__ scores)
{
    const int b     = blockIdx.x >> 5;
    const int chunk = blockIdx.x & (NC - 1);
    const int wave  = threadIdx.x >> 6;
    const int lane  = threadIdx.x & 63;
    constexpr int TPW = TC / 4;                 // 16 timesteps per wave
    const int t0 = chunk * TC + wave * TPW;

    // lane-owned fragment: d = {lane*4..+3} + 256*i for i in 0..3
    // (i=0,1 -> direction 0 chunk; i=2,3 -> direction 1 chunk)
    float4 q[4];
    const float4* qv = (const float4*)(query + b * DH);
    #pragma unroll
    for (int i = 0; i < 4; ++i) q[i] = qv[lane + 64 * i];

    float4 a[4] = {{0,0,0,0},{0,0,0,0},{0,0,0,0},{0,0,0,0}};
    float lacc = 0.f;
    const long dir1 = (long)Tt * Bb * Hh;       // offset of direction-1 plane

    for (int tt = 0; tt < TPW; tt += 2) {
        const int ta = t0 + tt, tb = ta + 1;
        const float* pa0 = enc_h + ((long)ta * Bb + b) * Hh;
        const float* pb0 = enc_h + ((long)tb * Bb + b) * Hh;
        float4 ka[4], kb[4];
        ka[0] = ((const float4*)pa0)[lane];
        ka[1] = ((const float4*)pa0)[lane + 64];
        ka[2] = ((const float4*)(pa0 + dir1))[lane];
        ka[3] = ((const float4*)(pa0 + dir1))[lane + 64];
        kb[0] = ((const float4*)pb0)[lane];
        kb[1] = ((const float4*)pb0)[lane + 64];
        kb[2] = ((const float4*)(pb0 + dir1))[lane];
        kb[3] = ((const float4*)(pb0 + dir1))[lane + 64];

        float sa = 0.f, sb = 0.f;
        #pragma unroll
        for (int i = 0; i < 4; ++i) { sa += dot4(q[i], ka[i]); sb += dot4(q[i], kb[i]); }
        #pragma unroll
        for (int off = 32; off; off >>= 1) {
            sa += __shfl_xor(sa, off, 64);
            sb += __shfl_xor(sb, off, 64);
        }
        const float pea = __expf(sa * SCALE);
        const float peb = __expf(sb * SCALE);
        lacc += pea + peb;
        #pragma unroll
        for (int i = 0; i < 4; ++i) { fma4(a[i], pea, ka[i]); fma4(a[i], peb, kb[i]); }
        if (lane == 0) {
            scores[b * Tt + ta] = pea;          // unnormalized; K3 divides by l
            scores[b * Tt + tb] = peb;
        }
    }

    // combine 4 waves in LDS, then one global atomicAdd per (b,d)
    __shared__ float s_acc[4][DH];
    __shared__ float s_l[4];
    #pragma unroll
    for (int i = 0; i < 4; ++i) ((float4*)s_acc[wave])[lane + 64 * i] = a[i];
    if (lane == 0) s_l[wave] = lacc;
    __syncthreads();

    const int tid = threadIdx.x;
    #pragma unroll
    for (int k = 0; k < 4; ++k) {
        const int d = tid * 4 + k;
        atomicAdd(&acc[b * DH + d],
                  s_acc[0][d] + s_acc[1][d] + s_acc[2][d] + s_acc[3][d]);
    }
    if (tid == 0) atomicAdd(&lsum[b], s_l[0] + s_l[1] + s_l[2] + s_l[3]);
}

// K3: normalize values and scores by 1/l[b]. grid 32, 256 threads.
__global__ __launch_bounds__(256) void norm_kernel(
    const float* __restrict__ acc, const float* __restrict__ lsum,
    float* __restrict__ out_values, float* __restrict__ scores)
{
    const int b = blockIdx.x;
    const float rinv = 1.0f / lsum[b];
    const int tid = threadIdx.x;
    #pragma unroll
    for (int d = tid; d < DH; d += 256)
        out_values[b * DH + d] = acc[b * DH + d] * rinv;
    #pragma unroll
    for (int t = tid; t < Tt; t += 256)
        scores[b * Tt + t] *= rinv;
}

extern "C" void kernel_launch(void* const* d_in, const int* in_sizes, int n_in,
                              void* d_out, int out_size, void* d_ws, size_t ws_size,
                              hipStream_t stream) {
    const float* input = (const float*)d_in[0];
    const float* enc_h = (const float*)d_in[1];
    // d_in[2] = decoder_state (unused), d_in[5] = t (unused)
    const float* Wq = (const float*)d_in[3];
    const float* bq = (const float*)d_in[4];

    float* out        = (float*)d_out;
    float* values_out = out;              // (32,1024)
    float* scores_out = out + Bb * DH;    // (32,2048,1)

    // workspace layout (floats): [query 32768 | acc 32768 | lsum 32]
    float* ws    = (float*)d_ws;
    float* query = ws;
    float* acc   = ws + Bb * DH;
    float* lsum  = ws + 2 * Bb * DH;

    qproj_kernel<<<512, 256, 0, stream>>>(input, Wq, bq, query, acc);
    attn_kernel<<<Bb * NC, 256, 0, stream>>>(enc_h, query, acc, lsum, scores_out);
    norm_kernel<<<Bb, 256, 0, stream>>>(acc, lsum, values_out, scores_out);
}

// Round 2
// 386.992 us; speedup vs baseline: 1.0056x; 1.0056x over previous
//
#include <hip/hip_runtime.h>
#include <math.h>

// Problem constants (from reference):
//   input (32,1024) f32; enc_h (2,2048,32,512) f32; Wq (1024,1024); bq (1024)
//   out = [attn_values (32,1024) | attn_scores (32,2048,1)] f32, 98304 floats
namespace {
constexpr int Bb = 32;
constexpr int Tt = 2048;
constexpr int Cc = 1024;
constexpr int Hh = 512;
constexpr int DH = 1024;          // D*HIDDEN
constexpr int NC = 32;            // t-chunks per batch row
constexpr int TC = Tt / NC;       // 64 timesteps per block
constexpr float SCALE = 0.04419417382415922f;  // 1/sqrt(512)
}

__device__ __forceinline__ float dot4(const float4& x, const float4& y) {
    return x.x * y.x + x.y * y.y + x.z * y.z + x.w * y.w;
}
__device__ __forceinline__ void fma4(float4& a, float p, const float4& k) {
    a.x += p * k.x; a.y += p * k.y; a.z += p * k.z; a.w += p * k.w;
}

// K1: query = input @ Wq.T + bq   (also zeroes acc/lsum scratch for K2)
// grid 512 = 32 b * 16 j-chunks, 256 threads.
// All 64 row-loads issue as independent streams (per-lane partials);
// 16 butterfly reductions run pipelined at the end, off the load path.
__global__ __launch_bounds__(256) void qproj_kernel(
    const float* __restrict__ input, const float* __restrict__ Wq,
    const float* __restrict__ bq, float* __restrict__ query,
    float* __restrict__ zero_region)
{
    const int gid = blockIdx.x * 256 + threadIdx.x;
    if (gid < Bb * DH + Bb) zero_region[gid] = 0.0f;   // acc + lsum := 0

    __shared__ float s_in[Cc];
    const int b   = blockIdx.x >> 4;
    const int jc  = blockIdx.x & 15;
    const int tid = threadIdx.x;
    ((float4*)s_in)[tid] = ((const float4*)(input + b * Cc))[tid];
    __syncthreads();

    const int wave = tid >> 6, lane = tid & 63;
    float4 x4[4];
    #pragma unroll
    for (int i = 0; i < 4; ++i) x4[i] = ((const float4*)s_in)[lane + 64 * i];

    const int jbase = jc * 64 + wave * 16;
    float partial[16];
    #pragma unroll
    for (int jj = 0; jj < 16; ++jj) {
        const float4* wrow = (const float4*)(Wq + (jbase + jj) * Cc);
        float p = 0.f;
        #pragma unroll
        for (int i = 0; i < 4; ++i) p += dot4(wrow[lane + 64 * i], x4[i]);
        partial[jj] = p;
    }
    #pragma unroll
    for (int off = 32; off; off >>= 1) {
        #pragma unroll
        for (int jj = 0; jj < 16; ++jj)
            partial[jj] += __shfl_xor(partial[jj], off, 64);
    }
    #pragma unroll
    for (int jj = 0; jj < 16; ++jj)
        if (lane == jj) query[b * DH + jbase + jj] = partial[jj] + bq[jbase + jj];
}

// K2: fused scores + exp + value accumulation (single pass over enc_h).
// Softmax shift-invariance + tiny |s| (<~0.8) => no max subtraction needed.
// grid 1024 = 32 b * 32 chunks, 256 threads (4 waves, 16 t each, 4-t unroll:
// 16 KB of loads in flight per wave, 4 independent reduce chains pipelined).
__global__ __launch_bounds__(256) void attn_kernel(
    const float* __restrict__ enc_h, const float* __restrict__ query,
    float* __restrict__ acc, float* __restrict__ lsum,
    float* __restrict__ scores)
{
    const int b     = blockIdx.x >> 5;
    const int chunk = blockIdx.x & (NC - 1);
    const int wave  = threadIdx.x >> 6;
    const int lane  = threadIdx.x & 63;
    constexpr int TPW = TC / 4;                 // 16 timesteps per wave
    const int t0 = chunk * TC + wave * TPW;

    // lane-owned fragment: d = {lane*4..+3} + 256*i for i in 0..3
    float4 q[4];
    const float4* qv = (const float4*)(query + b * DH);
    #pragma unroll
    for (int i = 0; i < 4; ++i) q[i] = qv[lane + 64 * i];

    float4 a[4] = {{0,0,0,0},{0,0,0,0},{0,0,0,0},{0,0,0,0}};
    float lacc = 0.f;
    const long dir1 = (long)Tt * Bb * Hh;       // offset of direction-1 plane

    for (int tt = 0; tt < TPW; tt += 4) {
        const int ta = t0 + tt;
        const float* p0 = enc_h + ((long)(ta + 0) * Bb + b) * Hh;
        const float* p1 = enc_h + ((long)(ta + 1) * Bb + b) * Hh;
        const float* p2 = enc_h + ((long)(ta + 2) * Bb + b) * Hh;
        const float* p3 = enc_h + ((long)(ta + 3) * Bb + b) * Hh;
        float4 k0[4], k1[4], k2[4], k3[4];
        #pragma unroll
        for (int i = 0; i < 2; ++i) {
            k0[i] = ((const float4*)p0)[lane + 64 * i];
            k1[i] = ((const float4*)p1)[lane + 64 * i];
            k2[i] = ((const float4*)p2)[lane + 64 * i];
            k3[i] = ((const float4*)p3)[lane + 64 * i];
            k0[i + 2] = ((const float4*)(p0 + dir1))[lane + 64 * i];
            k1[i + 2] = ((const float4*)(p1 + dir1))[lane + 64 * i];
            k2[i + 2] = ((const float4*)(p2 + dir1))[lane + 64 * i];
            k3[i + 2] = ((const float4*)(p3 + dir1))[lane + 64 * i];
        }

        float s0 = 0.f, s1 = 0.f, s2 = 0.f, s3 = 0.f;
        #pragma unroll
        for (int i = 0; i < 4; ++i) {
            s0 += dot4(q[i], k0[i]); s1 += dot4(q[i], k1[i]);
            s2 += dot4(q[i], k2[i]); s3 += dot4(q[i], k3[i]);
        }
        #pragma unroll
        for (int off = 32; off; off >>= 1) {   // 4 independent chains, pipelined
            s0 += __shfl_xor(s0, off, 64);
            s1 += __shfl_xor(s1, off, 64);
            s2 += __shfl_xor(s2, off, 64);
            s3 += __shfl_xor(s3, off, 64);
        }
        const float pe0 = __expf(s0 * SCALE);
        const float pe1 = __expf(s1 * SCALE);
        const float pe2 = __expf(s2 * SCALE);
        const float pe3 = __expf(s3 * SCALE);
        lacc += (pe0 + pe1) + (pe2 + pe3);
        #pragma unroll
        for (int i = 0; i < 4; ++i) {
            fma4(a[i], pe0, k0[i]); fma4(a[i], pe1, k1[i]);
            fma4(a[i], pe2, k2[i]); fma4(a[i], pe3, k3[i]);
        }
        if (lane == 0) {
            float4 sc = {pe0, pe1, pe2, pe3};   // unnormalized; K3 divides by l
            *((float4*)(scores + b * Tt + ta)) = sc;
        }
    }

    // combine 4 waves in LDS, then one global atomicAdd per (b,d)
    __shared__ float s_acc[4][DH];
    __shared__ float s_l[4];
    #pragma unroll
    for (int i = 0; i < 4; ++i) ((float4*)s_acc[wave])[lane + 64 * i] = a[i];
    if (lane == 0) s_l[wave] = lacc;
    __syncthreads();

    const int tid = threadIdx.x;
    #pragma unroll
    for (int k = 0; k < 4; ++k) {
        const int d = tid * 4 + k;
        atomicAdd(&acc[b * DH + d],
                  s_acc[0][d] + s_acc[1][d] + s_acc[2][d] + s_acc[3][d]);
    }
    if (tid == 0) atomicAdd(&lsum[b], s_l[0] + s_l[1] + s_l[2] + s_l[3]);
}

// K3: normalize values and scores by 1/l[b]. grid 32, 256 threads, float4.
__global__ __launch_bounds__(256) void norm_kernel(
    const float* __restrict__ acc, const float* __restrict__ lsum,
    float* __restrict__ out_values, float* __restrict__ scores)
{
    const int b = blockIdx.x;
    const float rinv = 1.0f / lsum[b];
    const int tid = threadIdx.x;
    {
        float4 v = ((const float4*)(acc + b * DH))[tid];
        v.x *= rinv; v.y *= rinv; v.z *= rinv; v.w *= rinv;
        ((float4*)(out_values + b * DH))[tid] = v;
    }
    #pragma unroll
    for (int r = 0; r < 2; ++r) {
        const int idx = tid + 256 * r;
        float4 s = ((float4*)(scores + b * Tt))[idx];
        s.x *= rinv; s.y *= rinv; s.z *= rinv; s.w *= rinv;
        ((float4*)(scores + b * Tt))[idx] = s;
    }
}

extern "C" void kernel_launch(void* const* d_in, const int* in_sizes, int n_in,
                              void* d_out, int out_size, void* d_ws, size_t ws_size,
                              hipStream_t stream) {
    const float* input = (const float*)d_in[0];
    const float* enc_h = (const float*)d_in[1];
    // d_in[2] = decoder_state (unused), d_in[5] = t (unused)
    const float* Wq = (const float*)d_in[3];
    const float* bq = (const float*)d_in[4];

    float* out        = (float*)d_out;
    float* values_out = out;              // (32,1024)
    float* scores_out = out + Bb * DH;    // (32,2048,1)

    // workspace layout (floats): [query 32768 | acc 32768 | lsum 32]
    float* ws    = (float*)d_ws;
    float* query = ws;
    float* acc   = ws + Bb * DH;
    float* lsum  = ws + 2 * Bb * DH;

    qproj_kernel<<<512, 256, 0, stream>>>(input, Wq, bq, query, acc);
    attn_kernel<<<Bb * NC, 256, 0, stream>>>(enc_h, query, acc, lsum, scores_out);
    norm_kernel<<<Bb, 256, 0, stream>>>(acc, lsum, values_out, scores_out);
}